// Round 7
// baseline (3234.100 us; speedup 1.0000x reference)
//
#include <hip/hip_runtime.h>
#include <math.h>

#define BATCH   8
#define NPTS    32768
#define FDIM    32
#define NGROUP  1024
#define GSIZE   32
#define KLANE   8       // per-lane candidate list length in KNN

// Multi-block FPS config: 8 blocks/batch x 512 threads x 8 pts/thread = 32768.
#define NBLK    8
#define FTPB    512
#define CHUNK   (NPTS / NBLK)   // 4096 points per block

// Exact float32 distance in the reference's association: ((dx^2+dy^2)+dz^2),
// contraction blocked so bits match the numpy ref (argmax stability).
__device__ __forceinline__ float dist2f(float ax, float ay, float az,
                                        float bx, float by, float bz) {
  float dx = __fsub_rn(ax, bx);
  float dy = __fsub_rn(ay, by);
  float dz = __fsub_rn(az, bz);
  return __fadd_rn(__fadd_rn(__fmul_rn(dx, dx), __fmul_rn(dy, dy)),
                   __fmul_rn(dz, dz));
}

#define X8(M) M(0) M(1) M(2) M(3) M(4) M(5) M(6) M(7)

// ---------------------------------------------------------------------------
// Kernel A: farthest point sampling, 8 blocks per batch (64 blocks total).
// R5 post-mortem: with batch = gb>>3, a batch's 8 blocks spread across all
// 8 XCDs (round-robin blockIdx%8 -> XCD), making every publish/poll a
// cross-die round trip (~6.1k cyc/iter). R6: batch = gb&7, bk = gb>>3 ->
// all 8 blocks of a batch co-resident on ONE XCD, slot line stays in that
// XCD's L2. Pure locality heuristic; correctness identical either way.
// Cross-block sync per iteration: each block publishes a packed candidate
// (tag<<47 | distbits<<15 | (0x7FFF-idx)) to its slot, polls all 8 slots of
// its batch for tag==t; max of packed = global argmax with numpy tie-break.
// Slots ping-pong on t&1 so a fast block's t+1 store can't clobber a value
// a slow block still needs at t.
// ---------------------------------------------------------------------------
__global__ __launch_bounds__(FTPB) void fps_kernel(
    const float* __restrict__ coord,
    unsigned long long* __restrict__ slots,   // [2][BATCH*NBLK], pre-zeroed
    int* __restrict__ s_idx_out) {
  const int gb   = blockIdx.x;        // 0..63
  const int b    = gb & 7;            // batch  (== XCD id under %8 mapping)
  const int bk   = gb >> 3;           // block within batch
  const int tid  = threadIdx.x;
  const int lane = tid & 63;
  const int wid  = tid >> 6;          // 0..7
  const float* __restrict__ c = coord + (size_t)b * NPTS * 3;
  const float3* __restrict__ c3 = (const float3*)c;

  __shared__ float redv[8];
  __shared__ int   redp[8];
  __shared__ unsigned long long bcast;

  const int pbase = bk * CHUNK + tid; // + i*FTPB

#define DECL8(i) float x##i, y##i, z##i, d##i;
  X8(DECL8)
#undef DECL8

  // Init: load owned points, distance to batch point 0, local argmax
  // (ascending point index + strict > == np.argmax lowest-index tie-break).
  float qx = c[0], qy = c[1], qz = c[2];
  float bestv = -1.0f; int bestp = 0;
#define LOAD8(i) { int p = pbase + (i) * FTPB; float3 v = c3[p];            \
    x##i = v.x; y##i = v.y; z##i = v.z;                                      \
    float t2 = dist2f(v.x, v.y, v.z, qx, qy, qz); d##i = t2;                 \
    if (t2 > bestv) { bestv = t2; bestp = p; } }
  X8(LOAD8)
#undef LOAD8

  if (bk == 0 && tid == 0) s_idx_out[b * NGROUP + 0] = 0;

  for (int t = 1; t < NGROUP; ++t) {
    // Wave-level argmax (max value, tie -> min index).
    float v = bestv; int p = bestp;
    #pragma unroll
    for (int m = 1; m < 64; m <<= 1) {
      float ov = __shfl_xor(v, m, 64);
      int   op = __shfl_xor(p, m, 64);
      if (ov > v || (ov == v && op < p)) { v = ov; p = op; }
    }
    if (lane == 0) { redv[wid] = v; redp[wid] = p; }
    __syncthreads();   // B1

    if (wid == 0) {
      // Block-level argmax over the 8 wave candidates (replicated butterfly).
      float gv = redv[lane & 7]; int gp = redp[lane & 7];
      #pragma unroll
      for (int m = 1; m < 8; m <<= 1) {
        float ov = __shfl_xor(gv, m, 64);
        int   op = __shfl_xor(gp, m, 64);
        if (ov > gv || (ov == gv && op < gp)) { gv = ov; gp = op; }
      }
      unsigned long long* base = slots + (size_t)(t & 1) * (BATCH * NBLK);
      if (lane == 0) {
        unsigned long long pk = ((unsigned long long)t << 47)
                              | ((unsigned long long)__float_as_uint(gv) << 15)
                              | (unsigned long long)(0x7FFF - gp);
        __hip_atomic_store(base + (b << 3) + bk, pk, __ATOMIC_RELEASE,
                           __HIP_MEMORY_SCOPE_AGENT);
      }
      // Poll: lanes 0..7 each watch one slot of this batch until tag == t.
      unsigned long long pk2 = 0;
      if (lane < 8) {
        const unsigned long long* sl = base + (b << 3) + lane;
        do {
          pk2 = __hip_atomic_load(sl, __ATOMIC_ACQUIRE,
                                  __HIP_MEMORY_SCOPE_AGENT);
        } while ((int)(pk2 >> 47) != t);
      }
      #pragma unroll
      for (int m = 1; m < 8; m <<= 1) {
        unsigned long long o = __shfl_xor(pk2, m, 64);
        if (o > pk2) pk2 = o;
      }
      if (lane == 0) bcast = pk2;
    }
    __syncthreads();   // B2

    const unsigned long long wpk = bcast;
    const int gp = 0x7FFF - (int)(wpk & 0x7FFF);
    if (bk == 0 && tid == 0) s_idx_out[b * NGROUP + t] = gp;
    if (t == NGROUP - 1) break;

    // Fetch winner coords (same-address wave load, L1/L2-resident) + update.
    float3 q = c3[gp];
    qx = q.x; qy = q.y; qz = q.z;
    bestv = -1.0f; bestp = 0;
#define UPD8(i) { float t2 = dist2f(x##i, y##i, z##i, qx, qy, qz);           \
    float nd = fminf(d##i, t2); d##i = nd;                                   \
    if (nd > bestv) { bestv = nd; bestp = pbase + (i) * FTPB; } }
    X8(UPD8)
#undef UPD8
  }
}

// ---------------------------------------------------------------------------
// Kernel B: one wave per sampled point. Brute-force 32-NN (per-lane sorted
// top-8 over its 512 strided points, then 32 wave-argmin extractions),
// then the feature-angle curvature and all 5 outputs.
// ---------------------------------------------------------------------------
__global__ __launch_bounds__(256) void knn_kernel(
    const float* __restrict__ coord, const float* __restrict__ feat,
    const int* __restrict__ labels, const int* __restrict__ s_idx_ws,
    float* __restrict__ out) {
  const int lane = threadIdx.x & 63;
  const int qid  = (blockIdx.x << 2) + (threadIdx.x >> 6);  // 0..8191
  const int b    = qid >> 10;
  const float* __restrict__ c = coord + (size_t)b * NPTS * 3;

  int sp = __builtin_amdgcn_readfirstlane(s_idx_ws[qid]);
  const int gq = b * NPTS + sp;
  const float qx = coord[(size_t)gq * 3 + 0];
  const float qy = coord[(size_t)gq * 3 + 1];
  const float qz = coord[(size_t)gq * 3 + 2];

  // Per-lane ascending top-8 (value, index), static indexing only.
  float lv[KLANE]; int li[KLANE];
  #pragma unroll
  for (int j = 0; j < KLANE; ++j) { lv[j] = 1e30f; li[j] = 0x7fffffff; }

  for (int s = 0; s < NPTS / 64; ++s) {
    int p = (s << 6) + lane;
    float3 v = ((const float3*)c)[p];
    float d2 = dist2f(v.x, v.y, v.z, qx, qy, qz);
    if (d2 < lv[KLANE - 1]) {
      // Branchless unrolled sorted insert; strict < keeps equal-distance
      // earlier (lower) indices first, matching lax.top_k tie order.
      #pragma unroll
      for (int j = KLANE - 1; j >= 1; --j) {
        bool up = d2 < lv[j - 1];
        float nv = up ? lv[j - 1] : ((d2 < lv[j]) ? d2 : lv[j]);
        int   ni = up ? li[j - 1] : ((d2 < lv[j]) ? p  : li[j]);
        lv[j] = nv; li[j] = ni;
      }
      if (d2 < lv[0]) { lv[0] = d2; li[0] = p; }
    }
  }

  // Extract the 32 globally smallest (ascending, tie -> lower index).
  // Round 0 is the query itself (d2 == 0), excluded from the angle mean
  // like angles[:, :, 1:].
  int nbp = 0;
  for (int r = 0; r < GSIZE; ++r) {
    float mv = lv[0]; int mp = li[0];
    #pragma unroll
    for (int m = 1; m < 64; m <<= 1) {
      float ov = __shfl_xor(mv, m, 64);
      int   op = __shfl_xor(mp, m, 64);
      if (ov < mv || (ov == mv && op < mp)) { mv = ov; mp = op; }
    }
    if (lane == r) nbp = mp;
    if (lv[0] == mv && li[0] == mp) {  // unique winner pops its head
      #pragma unroll
      for (int j = 0; j < KLANE - 1; ++j) { lv[j] = lv[j + 1]; li[j] = li[j + 1]; }
      lv[KLANE - 1] = 1e30f; li[KLANE - 1] = 0x7fffffff;
    }
  }

  // Angle for lanes 1..31: theta = 2*atan2(||a*|b| - |a|*b||, ||a*|b| + |a|*b||)
  const float* aRow = feat + (size_t)gq * FDIM;
  float my_a = (lane < FDIM) ? aRow[lane] : 0.0f;

  float ang = 0.0f;
  if (lane >= 1 && lane < GSIZE) {
    const float4* a4 = (const float4*)aRow;
    const float4* b4 = (const float4*)(feat + ((size_t)b * NPTS + nbp) * FDIM);
    float4 av[FDIM / 4], bv[FDIM / 4];
    float aa = 0.0f, bb = 0.0f;
    #pragma unroll
    for (int k = 0; k < FDIM / 4; ++k) {
      av[k] = a4[k]; bv[k] = b4[k];
      aa += av[k].x * av[k].x + av[k].y * av[k].y + av[k].z * av[k].z + av[k].w * av[k].w;
      bb += bv[k].x * bv[k].x + bv[k].y * bv[k].y + bv[k].z * bv[k].z + bv[k].w * bv[k].w;
    }
    float an = sqrtf(aa), bn = sqrtf(bb);
    float num2 = 0.0f, den2 = 0.0f;
    #pragma unroll
    for (int k = 0; k < FDIM / 4; ++k) {
      float n0 = av[k].x * bn - an * bv[k].x, dd0 = av[k].x * bn + an * bv[k].x;
      float n1 = av[k].y * bn - an * bv[k].y, dd1 = av[k].y * bn + an * bv[k].y;
      float n2 = av[k].z * bn - an * bv[k].z, dd2 = av[k].z * bn + an * bv[k].z;
      float n3 = av[k].w * bn - an * bv[k].w, dd3 = av[k].w * bn + an * bv[k].w;
      num2 += n0 * n0 + n1 * n1 + n2 * n2 + n3 * n3;
      den2 += dd0 * dd0 + dd1 * dd1 + dd2 * dd2 + dd3 * dd3;
    }
    ang = 2.0f * atan2f(sqrtf(num2), sqrtf(den2));
  }

  // Wave sum of the 31 angles -> p_curv everywhere.
  float tot = ang;
  #pragma unroll
  for (int m = 1; m < 64; m <<= 1) tot += __shfl_xor(tot, m, 64);
  float p_curv = tot / 31.0f;

  // Outputs (flat concatenation, all as float32).
  float* out_xyz  = out;                              // 8192*3
  float* out_feat = out + (size_t)BATCH * NGROUP * 3; // 8192*33
  float* out_sw   = out_feat + (size_t)BATCH * NGROUP * (FDIM + 1);
  float* out_lab  = out_sw  + (size_t)BATCH * NGROUP;
  float* out_sif  = out_lab + (size_t)BATCH * NGROUP;

  if (lane < FDIM)  out_feat[(size_t)qid * (FDIM + 1) + lane] = my_a;
  if (lane == FDIM) out_feat[(size_t)qid * (FDIM + 1) + FDIM] = p_curv;
  if (lane == 0) {
    out_xyz[(size_t)qid * 3 + 0] = qx;
    out_xyz[(size_t)qid * 3 + 1] = qy;
    out_xyz[(size_t)qid * 3 + 2] = qz;
    out_sw[qid]  = (p_curv > 0.087266f) ? 1.0f : 0.0f;
    out_lab[qid] = (float)labels[gq];
    out_sif[qid] = (float)gq;   // s_idx + b*N
  }
}

extern "C" void kernel_launch(void* const* d_in, const int* in_sizes, int n_in,
                              void* d_out, int out_size, void* d_ws, size_t ws_size,
                              hipStream_t stream) {
  const float* coord  = (const float*)d_in[0];
  const float* feat   = (const float*)d_in[1];
  const int*   labels = (const int*)d_in[2];

  // ws layout: [2][64] u64 ping-pong slots (zeroed), then 8*1024 int s_idx.
  unsigned long long* slots = (unsigned long long*)d_ws;
  int* s_idx_ws = (int*)((char*)d_ws + 2 * BATCH * NBLK * sizeof(unsigned long long));

  hipMemsetAsync(d_ws, 0, 2 * BATCH * NBLK * sizeof(unsigned long long), stream);
  fps_kernel<<<BATCH * NBLK, FTPB, 0, stream>>>(coord, slots, s_idx_ws);
  knn_kernel<<<(BATCH * NGROUP) / 4, 256, 0, stream>>>(coord, feat, labels,
                                                       s_idx_ws, (float*)d_out);
}